// Round 7
// baseline (234.093 us; speedup 1.0000x reference)
//
#include <hip/hip_runtime.h>
#include <hip/hip_bf16.h>

typedef __attribute__((ext_vector_type(4))) float  f32x4;
typedef __attribute__((ext_vector_type(16))) float f32x16;
typedef __attribute__((ext_vector_type(8))) short  s16x8;
typedef __attribute__((ext_vector_type(4))) short  s16x4;

#define THR_  1.0e-4f   // LR * GAMMA
#define SC_   2.0e-3f   // 2 * LR

__device__ __forceinline__ unsigned short f2bf(float f) {
  union { __hip_bfloat16 b; unsigned short u; } cv;
  cv.b = __float2bfloat16(f);
  return cv.u;
}
__device__ __forceinline__ float sthr(float v) {
  return v - fmaxf(fminf(v, THR_), -THR_);   // med3 + sub
}
__device__ __forceinline__ float bflo(unsigned u) {
  return __builtin_bit_cast(float, u << 16);
}
__device__ __forceinline__ float bfhi(unsigned u) {
  return __builtin_bit_cast(float, u & 0xffff0000u);
}

// A-frag packing for 32x32x16 (A[row][k]): lane l holds row=(l&31), k=8*(l>>5)+j.
// ws layout (unsigned short elems):
// [0,65536)     Gpk: A-frags of (-2LR*G), G=W@W^T (symmetric). frag(kc 0..15, ntg 0..7)
// [65536,98304) Cpk: A-frags of (2LR*W). frag(kc 0..7, ntg 0..7)
// [98304,131072) Opk: A-frags of W^T. frag(kc 0..15, it 0..3)
__global__ void sc_prep(const float* __restrict__ W, unsigned short* __restrict__ ws) {
  const int b = blockIdx.x;
  const int l = threadIdx.x;
  const int r = l & 31, h = l >> 5;
  if (b < 128) {                        // Gpk
    const int kc = b >> 3, ntg = b & 7;
    const int n = ntg * 32 + r;
    const int k0 = kc * 16 + 8 * h;
    float s[8];
    #pragma unroll
    for (int j = 0; j < 8; ++j) s[j] = 0.0f;
    for (int i = 0; i < 128; ++i) {
      const float wn = W[n * 128 + i];
      #pragma unroll
      for (int j = 0; j < 8; ++j) s[j] += W[(k0 + j) * 128 + i] * wn;
    }
    unsigned short* dst = ws + ((unsigned)b * 64u + l) * 8u;
    #pragma unroll
    for (int j = 0; j < 8; ++j) dst[j] = f2bf(-SC_ * s[j]);
  } else if (b < 192) {                 // Cpk
    const int bb = b - 128;
    const int kc = bb >> 3, ntg = bb & 7;
    const int n = ntg * 32 + r;
    const int k0 = kc * 16 + 8 * h;
    unsigned short* dst = ws + 65536u + ((unsigned)bb * 64u + l) * 8u;
    #pragma unroll
    for (int j = 0; j < 8; ++j) dst[j] = f2bf(SC_ * W[n * 128 + k0 + j]);
  } else {                              // Opk
    const int bb = b - 192;
    const int kc = bb >> 2, it = bb & 3;
    const int i = it * 32 + r;
    const int n0 = kc * 16 + 8 * h;
    unsigned short* dst = ws + 98304u + ((unsigned)bb * 64u + l) * 8u;
    #pragma unroll
    for (int j = 0; j < 8; ++j) dst[j] = f2bf(W[(n0 + j) * 128 + i]);
  }
}

// Two-tile pipelined structure: tiles T (rows 0-31) and U (rows 32-63) per
// 256-thr block. Phase A: T.mfma || U.writeback; [B]; Phase B: U.mfma ||
// T.writeback; [B]. The other tile's independent VALU/DS work fills every
// ds_read-latency window and MFMA dependency bubble by construction.
// Buffers: TA=0, TB=16640, UA=33280, UB=49920 (row stride 520 B, 2-way max).
// creg packed bf16x2 (32 regs for both tiles) to keep total ~224 regs.
// NOTE: working set ~224+ regs -> ONLY __launch_bounds__(256,2) is legal
// ((256,4) caps allocator at 128 and spills GBs to scratch: R2/R4).
__global__ __launch_bounds__(256, 2) void sc_fused(
    const float* __restrict__ inp,
    const unsigned short* __restrict__ wsp,
    float* __restrict__ outp)
{
  __shared__ __align__(16) unsigned char lds[66560];

  if ((blockIdx.x >> 8) & 1) {          // cross-block anti-phase nudge
    __builtin_amdgcn_s_sleep(15);
    __builtin_amdgcn_s_sleep(5);
  }

  const int tid = threadIdx.x;
  const int l = tid & 63;
  const int w = tid >> 6;          // 0..3
  const int h = l >> 5;            // 0..1
  const int r31 = l & 31;
  const long row0 = (long)blockIdx.x * 64;

  const int rB = r31 * 520 + h * 16;              // mfma-phase read base
  const int wB = r31 * 520 + h * 8 + w * 128;     // writeback base
  const int ob = r31 * 520 + w * 128 + h * 16;    // out-stage base

  // ---- stage 64 input rows -> TB/UB (bf16, stride 264) ----
  #pragma unroll
  for (int rep = 0; rep < 8; ++rep) {
    const int flat = rep * 256 + tid;            // 0..2047 float4s
    const int rr = flat >> 5;                    // 0..63
    const int c4 = flat & 31;
    const f32x4 v = *reinterpret_cast<const f32x4*>(inp + (row0 + rr) * 128 + c4 * 4);
    s16x4 p;
    p[0] = (short)f2bf(v[0]); p[1] = (short)f2bf(v[1]);
    p[2] = (short)f2bf(v[2]); p[3] = (short)f2bf(v[3]);
    const int base = 16640 + (rr >> 5) * 33280 + (rr & 31) * 264;
    *reinterpret_cast<s16x4*>(lds + base + c4 * 8) = p;
  }

  // ---- c-phase A-frags (2LR*W) ----
  s16x8 gfr[32];
  #pragma unroll
  for (int kc = 0; kc < 8; ++kc)
    #pragma unroll
    for (int nt = 0; nt < 2; ++nt)
      gfr[kc * 2 + nt] = *reinterpret_cast<const s16x8*>(
          wsp + 65536u + ((unsigned)(kc * 8 + w * 2 + nt) * 64u + l) * 8u);

  __syncthreads();

  // ---- c = 2LR * W @ in^T for both tiles ----
  f32x16 accT[2], accU[2];
  #pragma unroll
  for (int nt = 0; nt < 2; ++nt)
    #pragma unroll
    for (int e = 0; e < 16; ++e) { accT[nt][e] = 0.0f; accU[nt][e] = 0.0f; }

  const int ibT = 16640 + r31 * 264 + h * 16;
  const int ibU = ibT + 33280;
  #pragma unroll
  for (int kc = 0; kc < 8; ++kc) {
    const s16x8 bT = *reinterpret_cast<const s16x8*>(lds + ibT + kc * 32);
    const s16x8 bU = *reinterpret_cast<const s16x8*>(lds + ibU + kc * 32);
    __builtin_amdgcn_s_setprio(1);
    accT[0] = __builtin_amdgcn_mfma_f32_32x32x16_bf16(gfr[kc * 2 + 0], bT, accT[0], 0, 0, 0);
    accT[1] = __builtin_amdgcn_mfma_f32_32x32x16_bf16(gfr[kc * 2 + 1], bT, accT[1], 0, 0, 0);
    accU[0] = __builtin_amdgcn_mfma_f32_32x32x16_bf16(gfr[kc * 2 + 0], bU, accU[0], 0, 0, 0);
    accU[1] = __builtin_amdgcn_mfma_f32_32x32x16_bf16(gfr[kc * 2 + 1], bU, accU[1], 0, 0, 0);
    __builtin_amdgcn_s_setprio(0);
  }

  // pack c to bf16x2 (16 u32 per tile)
  unsigned cpT[16], cpU[16];
  #pragma unroll
  for (int nt = 0; nt < 2; ++nt)
    #pragma unroll
    for (int j = 0; j < 8; ++j) {
      cpT[nt * 8 + j] = (unsigned)f2bf(accT[nt][2 * j]) |
                        ((unsigned)f2bf(accT[nt][2 * j + 1]) << 16);
      cpU[nt * 8 + j] = (unsigned)f2bf(accU[nt][2 * j]) |
                        ((unsigned)f2bf(accU[nt][2 * j + 1]) << 16);
    }

  // T: x1 = sthr(c) -> TA(0); preinit accT = x1 + c_bf
  #pragma unroll
  for (int nt = 0; nt < 2; ++nt)
    #pragma unroll
    for (int q = 0; q < 4; ++q) {
      float x0 = sthr(accT[nt][4 * q + 0]), x1 = sthr(accT[nt][4 * q + 1]);
      float x2 = sthr(accT[nt][4 * q + 2]), x3 = sthr(accT[nt][4 * q + 3]);
      s16x4 p;
      p[0] = (short)f2bf(x0); p[1] = (short)f2bf(x1);
      p[2] = (short)f2bf(x2); p[3] = (short)f2bf(x3);
      *reinterpret_cast<s16x4*>(lds + 0 + wB + nt * 64 + q * 16) = p;
      const unsigned pa = cpT[nt * 8 + q * 2], pb = cpT[nt * 8 + q * 2 + 1];
      accT[nt][4 * q + 0] = x0 + bflo(pa); accT[nt][4 * q + 1] = x1 + bfhi(pa);
      accT[nt][4 * q + 2] = x2 + bflo(pb); accT[nt][4 * q + 3] = x3 + bfhi(pb);
    }

  // ---- step A-frags (-2LR*G) ----
  #pragma unroll
  for (int kc = 0; kc < 16; ++kc)
    #pragma unroll
    for (int nt = 0; nt < 2; ++nt)
      gfr[kc * 2 + nt] = *reinterpret_cast<const s16x8*>(
          wsp + ((unsigned)(kc * 8 + w * 2 + nt) * 64u + l) * 8u);

  // step-MFMA: acc += (-2LR*G) @ x^T (16 kc)
  auto MSTEP = [&](f32x16* acc, const int rbase) {
    __builtin_amdgcn_s_setprio(1);
    #pragma unroll
    for (int kc = 0; kc < 16; ++kc) {
      const s16x8 b = *reinterpret_cast<const s16x8*>(lds + rbase + rB + kc * 32);
      acc[0] = __builtin_amdgcn_mfma_f32_32x32x16_bf16(gfr[kc * 2 + 0], b, acc[0], 0, 0, 0);
      acc[1] = __builtin_amdgcn_mfma_f32_32x32x16_bf16(gfr[kc * 2 + 1], b, acc[1], 0, 0, 0);
    }
    __builtin_amdgcn_s_setprio(0);
  };
  // writeback: x = sthr(acc) -> wbase; preinit acc = x + c_bf
  auto WB = [&](f32x16* acc, const unsigned* cp, const int wbase) {
    #pragma unroll
    for (int nt = 0; nt < 2; ++nt)
      #pragma unroll
      for (int q = 0; q < 4; ++q) {
        float x0 = sthr(acc[nt][4 * q + 0]), x1 = sthr(acc[nt][4 * q + 1]);
        float x2 = sthr(acc[nt][4 * q + 2]), x3 = sthr(acc[nt][4 * q + 3]);
        s16x4 p;
        p[0] = (short)f2bf(x0); p[1] = (short)f2bf(x1);
        p[2] = (short)f2bf(x2); p[3] = (short)f2bf(x3);
        *reinterpret_cast<s16x4*>(lds + wbase + wB + nt * 64 + q * 16) = p;
        const unsigned pa = cp[nt * 8 + q * 2], pb = cp[nt * 8 + q * 2 + 1];
        acc[nt][4 * q + 0] = x0 + bflo(pa); acc[nt][4 * q + 1] = x1 + bfhi(pa);
        acc[nt][4 * q + 2] = x2 + bflo(pb); acc[nt][4 * q + 3] = x3 + bfhi(pb);
      }
  };

  __syncthreads();

  // ---- 9 pipelined iterations: one ISTA step for each tile per iteration ----
  // Invariants at phase A entry: accT = x_T + c (pre-init), x_T in bufT[par];
  //                              accU holds U's pre-sthr sum for x_{i+1}.
  #pragma unroll 1
  for (int i = 0; i < 9; ++i) {
    const int par = i & 1;
    // phase A: T computes, U writes back
    MSTEP(accT, par ? 16640 : 0);
    WB(accU, cpU, par ? 49920 : 33280);
    __syncthreads();
    // phase B: U computes (reads what it just wrote), T writes back
    MSTEP(accU, par ? 49920 : 33280);
    WB(accT, cpT, par ? 0 : 16640);
    __syncthreads();
  }
  // Now: x10_T in TB(16640); accU holds x10_U pre-sthr.

  // ---- epilogue: out^T = W^T @ x^T ----
  #pragma unroll
  for (int kc = 0; kc < 16; ++kc)
    gfr[kc] = *reinterpret_cast<const s16x8*>(
        wsp + 98304u + ((unsigned)(kc * 4 + w) * 64u + l) * 8u);

  // E1: T.out-mfma (reads TB) || U final writeback x10 -> UB
  #pragma unroll
  for (int e = 0; e < 16; ++e) accT[0][e] = 0.0f;
  __builtin_amdgcn_s_setprio(1);
  #pragma unroll
  for (int kc = 0; kc < 16; ++kc) {
    const s16x8 b = *reinterpret_cast<const s16x8*>(lds + 16640 + rB + kc * 32);
    accT[0] = __builtin_amdgcn_mfma_f32_32x32x16_bf16(gfr[kc], b, accT[0], 0, 0, 0);
  }
  __builtin_amdgcn_s_setprio(0);
  #pragma unroll
  for (int nt = 0; nt < 2; ++nt)
    #pragma unroll
    for (int q = 0; q < 4; ++q) {
      float x0 = sthr(accU[nt][4 * q + 0]), x1 = sthr(accU[nt][4 * q + 1]);
      float x2 = sthr(accU[nt][4 * q + 2]), x3 = sthr(accU[nt][4 * q + 3]);
      s16x4 p;
      p[0] = (short)f2bf(x0); p[1] = (short)f2bf(x1);
      p[2] = (short)f2bf(x2); p[3] = (short)f2bf(x3);
      *reinterpret_cast<s16x4*>(lds + 49920 + wB + nt * 64 + q * 16) = p;
    }
  __syncthreads();

  // E2: U.out-mfma (reads UB); stage both outputs f32 -> TA/UA
  #pragma unroll
  for (int e = 0; e < 16; ++e) accU[0][e] = 0.0f;
  __builtin_amdgcn_s_setprio(1);
  #pragma unroll
  for (int kc = 0; kc < 16; ++kc) {
    const s16x8 b = *reinterpret_cast<const s16x8*>(lds + 49920 + rB + kc * 32);
    accU[0] = __builtin_amdgcn_mfma_f32_32x32x16_bf16(gfr[kc], b, accU[0], 0, 0, 0);
  }
  __builtin_amdgcn_s_setprio(0);
  #pragma unroll
  for (int q = 0; q < 4; ++q) {
    f32x4 pT, pU;
    pT[0] = accT[0][4 * q + 0]; pT[1] = accT[0][4 * q + 1];
    pT[2] = accT[0][4 * q + 2]; pT[3] = accT[0][4 * q + 3];
    pU[0] = accU[0][4 * q + 0]; pU[1] = accU[0][4 * q + 1];
    pU[2] = accU[0][4 * q + 2]; pU[3] = accU[0][4 * q + 3];
    *reinterpret_cast<f32x4*>(lds + 0     + ob + q * 32) = pT;
    *reinterpret_cast<f32x4*>(lds + 33280 + ob + q * 32) = pU;
  }
  __syncthreads();

  // coalesced copy 64 rows x 128 f32 -> global
  #pragma unroll
  for (int rep = 0; rep < 8; ++rep) {
    const int flat = rep * 256 + tid;
    const int rr = flat >> 5;
    const int c4 = flat & 31;
    const int base = (rr >> 5) * 33280 + (rr & 31) * 520;
    const f32x4 v = *reinterpret_cast<const f32x4*>(lds + base + c4 * 16);
    *reinterpret_cast<f32x4*>(outp + (row0 + rr) * 128 + c4 * 4) = v;
  }
}

extern "C" void kernel_launch(void* const* d_in, const int* in_sizes, int n_in,
                              void* d_out, int out_size, void* d_ws, size_t ws_size,
                              hipStream_t stream) {
  const float* inp = (const float*)d_in[0];
  const float* W   = (const float*)d_in[1];
  unsigned short* ws = (unsigned short*)d_ws;   // needs 256 KiB
  float* outp = (float*)d_out;
  const int B = in_sizes[0] / 128;              // 131072
  sc_prep<<<256, 64, 0, stream>>>(W, ws);
  sc_fused<<<B / 64, 256, 0, stream>>>(inp, ws, outp);
}

// Round 8
// 219.244 us; speedup vs baseline: 1.0677x; 1.0677x over previous
//
#include <hip/hip_runtime.h>
#include <hip/hip_bf16.h>

typedef __attribute__((ext_vector_type(4))) float  f32x4;
typedef __attribute__((ext_vector_type(16))) float f32x16;
typedef __attribute__((ext_vector_type(8))) short  s16x8;
typedef __attribute__((ext_vector_type(4))) short  s16x4;

#define THR_  1.0e-4f   // LR * GAMMA
#define SC_   2.0e-3f   // 2 * LR

__device__ __forceinline__ unsigned short f2bf(float f) {
  union { __hip_bfloat16 b; unsigned short u; } cv;
  cv.b = __float2bfloat16(f);
  return cv.u;
}
__device__ __forceinline__ float sthr(float v) {
  return v - fmaxf(fminf(v, THR_), -THR_);   // med3 + sub
}
__device__ __forceinline__ float bflo(unsigned u) {
  return __builtin_bit_cast(float, u << 16);
}
__device__ __forceinline__ float bfhi(unsigned u) {
  return __builtin_bit_cast(float, u & 0xffff0000u);
}

// A-frag packing for 32x32x16 (A[row][k]): lane l holds row=(l&31), k=8*(l>>5)+j.
// ws layout (unsigned short elems):
// [0,65536)     Gpk: A-frags of (-2LR*G), G=W@W^T (symmetric). frag(kc 0..15, ntg 0..7)
// [65536,98304) Cpk: A-frags of (2LR*W). frag(kc 0..7, ntg 0..7)
// [98304,131072) Opk: A-frags of W^T. frag(kc 0..15, it 0..3)
__global__ void sc_prep(const float* __restrict__ W, unsigned short* __restrict__ ws) {
  const int b = blockIdx.x;
  const int l = threadIdx.x;
  const int r = l & 31, h = l >> 5;
  if (b < 128) {                        // Gpk
    const int kc = b >> 3, ntg = b & 7;
    const int n = ntg * 32 + r;
    const int k0 = kc * 16 + 8 * h;
    float s[8];
    #pragma unroll
    for (int j = 0; j < 8; ++j) s[j] = 0.0f;
    for (int i = 0; i < 128; ++i) {
      const float wn = W[n * 128 + i];
      #pragma unroll
      for (int j = 0; j < 8; ++j) s[j] += W[(k0 + j) * 128 + i] * wn;
    }
    unsigned short* dst = ws + ((unsigned)b * 64u + l) * 8u;
    #pragma unroll
    for (int j = 0; j < 8; ++j) dst[j] = f2bf(-SC_ * s[j]);
  } else if (b < 192) {                 // Cpk
    const int bb = b - 128;
    const int kc = bb >> 3, ntg = bb & 7;
    const int n = ntg * 32 + r;
    const int k0 = kc * 16 + 8 * h;
    unsigned short* dst = ws + 65536u + ((unsigned)bb * 64u + l) * 8u;
    #pragma unroll
    for (int j = 0; j < 8; ++j) dst[j] = f2bf(SC_ * W[n * 128 + k0 + j]);
  } else {                              // Opk
    const int bb = b - 192;
    const int kc = bb >> 2, it = bb & 3;
    const int i = it * 32 + r;
    const int n0 = kc * 16 + 8 * h;
    unsigned short* dst = ws + 98304u + ((unsigned)bb * 64u + l) * 8u;
    #pragma unroll
    for (int j = 0; j < 8; ++j) dst[j] = f2bf(W[(n0 + j) * 128 + i]);
  }
}

// Wave-partitioned anti-phase pipeline: 512 thr = 8 waves; waves 0-3 = tile T
// (rows 0-31), waves 4-7 = tile U (rows 32-63). Each SIMD hosts one T-wave +
// one U-wave. Per iteration: phase A = T.mfma || U.writeback; [bar];
// phase B = U.mfma || T.writeback; [bar]. Matrix bubbles of one wave are
// filled by the partner wave's VALU/DS work by construction.
// Per-wave regs = R6's proven footprint (gfr 128 + accA/accB 64 + cp 16).
// Buffers: TA=0, TB=16640, UA=33280, UB=49920 (row stride 520 B, 2-way max).
// NOTE: ONLY min-waves=2 launch bounds are legal (cap 256); higher mins
// spilled GBs to scratch in R2/R4/R7.
__global__ __launch_bounds__(512, 2) void sc_fused(
    const float* __restrict__ inp,
    const unsigned short* __restrict__ wsp,
    float* __restrict__ outp)
{
  __shared__ __align__(16) unsigned char lds[66560];

  const int tid = threadIdx.x;
  const int l = tid & 63;
  const int wv = tid >> 6;         // 0..7
  const int grp = wv >> 2;         // 0 = tile T, 1 = tile U
  const int w4 = wv & 3;           // n-panel owner within group
  const int h = l >> 5;
  const int r31 = l & 31;
  const long row0 = (long)blockIdx.x * 64;

  const int XA = grp * 33280;      // group's x buffer pair
  const int XB = XA + 16640;

  const int rB = r31 * 520 + h * 16;              // mfma-phase read base
  const int wB = r31 * 520 + h * 8 + w4 * 128;    // writeback base

  // ---- stage 64 input rows -> TB/UB (bf16, stride 264) ----
  #pragma unroll
  for (int rep = 0; rep < 4; ++rep) {
    const int flat = rep * 512 + tid;            // 0..2047 float4s
    const int rr = flat >> 5;                    // 0..63
    const int c4 = flat & 31;
    const f32x4 v = *reinterpret_cast<const f32x4*>(inp + (row0 + rr) * 128 + c4 * 4);
    s16x4 p;
    p[0] = (short)f2bf(v[0]); p[1] = (short)f2bf(v[1]);
    p[2] = (short)f2bf(v[2]); p[3] = (short)f2bf(v[3]);
    const int base = 16640 + (rr >> 5) * 33280 + (rr & 31) * 264;
    *reinterpret_cast<s16x4*>(lds + base + c4 * 8) = p;
  }

  // ---- c-phase A-frags (2LR*W) ----
  s16x8 gfr[32];
  #pragma unroll
  for (int kc = 0; kc < 8; ++kc)
    #pragma unroll
    for (int nt = 0; nt < 2; ++nt)
      gfr[kc * 2 + nt] = *reinterpret_cast<const s16x8*>(
          wsp + 65536u + ((unsigned)(kc * 8 + w4 * 2 + nt) * 64u + l) * 8u);

  __syncthreads();

  // ---- c = 2LR * W @ in^T (own tile only; K-split kc0-3->accA, 4-7->accB) ----
  f32x16 accA[2], accB[2];
  #pragma unroll
  for (int nt = 0; nt < 2; ++nt)
    #pragma unroll
    for (int e = 0; e < 16; ++e) { accA[nt][e] = 0.0f; accB[nt][e] = 0.0f; }

  const int ib = XB + r31 * 264 + h * 16;
  #pragma unroll
  for (int kc = 0; kc < 4; ++kc) {
    const s16x8 bA = *reinterpret_cast<const s16x8*>(lds + ib + kc * 32);
    const s16x8 bB = *reinterpret_cast<const s16x8*>(lds + ib + (kc + 4) * 32);
    __builtin_amdgcn_s_setprio(1);
    #pragma unroll
    for (int nt = 0; nt < 2; ++nt)
      accA[nt] = __builtin_amdgcn_mfma_f32_32x32x16_bf16(gfr[kc * 2 + nt], bA, accA[nt], 0, 0, 0);
    #pragma unroll
    for (int nt = 0; nt < 2; ++nt)
      accB[nt] = __builtin_amdgcn_mfma_f32_32x32x16_bf16(gfr[(kc + 4) * 2 + nt], bB, accB[nt], 0, 0, 0);
    __builtin_amdgcn_s_setprio(0);
  }

  // pack c to bf16x2; fold A+B
  unsigned cp[16];
  #pragma unroll
  for (int nt = 0; nt < 2; ++nt)
    #pragma unroll
    for (int j = 0; j < 8; ++j) {
      const float e0 = accA[nt][2 * j + 0] + accB[nt][2 * j + 0];
      const float e1 = accA[nt][2 * j + 1] + accB[nt][2 * j + 1];
      cp[nt * 8 + j] = (unsigned)f2bf(e0) | ((unsigned)f2bf(e1) << 16);
      accA[nt][2 * j + 0] = e0; accA[nt][2 * j + 1] = e1;   // sum in accA
      accB[nt][2 * j + 0] = 0.0f; accB[nt][2 * j + 1] = 0.0f;
    }

  // ---- step A-frags (-2LR*G) ----
  #pragma unroll
  for (int kc = 0; kc < 16; ++kc)
    #pragma unroll
    for (int nt = 0; nt < 2; ++nt)
      gfr[kc * 2 + nt] = *reinterpret_cast<const s16x8*>(
          wsp + ((unsigned)(kc * 8 + w4 * 2 + nt) * 64u + l) * 8u);

  // step-MFMA: acc += (-2LR*G) @ x^T, reading x from base (16 kc, K-split)
  auto MSTEP = [&](const int base) {
    #pragma unroll
    for (int kc = 0; kc < 8; ++kc) {
      const s16x8 bA = *reinterpret_cast<const s16x8*>(lds + base + rB + kc * 32);
      const s16x8 bB = *reinterpret_cast<const s16x8*>(lds + base + rB + (kc + 8) * 32);
      __builtin_amdgcn_s_setprio(1);
      #pragma unroll
      for (int nt = 0; nt < 2; ++nt)
        accA[nt] = __builtin_amdgcn_mfma_f32_32x32x16_bf16(gfr[kc * 2 + nt], bA, accA[nt], 0, 0, 0);
      #pragma unroll
      for (int nt = 0; nt < 2; ++nt)
        accB[nt] = __builtin_amdgcn_mfma_f32_32x32x16_bf16(gfr[(kc + 8) * 2 + nt], bB, accB[nt], 0, 0, 0);
      __builtin_amdgcn_s_setprio(0);
    }
  };
  // writeback: x = sthr(accA+accB) -> base; preinit accA = x + c_bf, accB = 0
  auto WB = [&](const int base) {
    #pragma unroll
    for (int nt = 0; nt < 2; ++nt)
      #pragma unroll
      for (int q = 0; q < 4; ++q) {
        float x0 = sthr(accA[nt][4 * q + 0] + accB[nt][4 * q + 0]);
        float x1 = sthr(accA[nt][4 * q + 1] + accB[nt][4 * q + 1]);
        float x2 = sthr(accA[nt][4 * q + 2] + accB[nt][4 * q + 2]);
        float x3 = sthr(accA[nt][4 * q + 3] + accB[nt][4 * q + 3]);
        s16x4 p;
        p[0] = (short)f2bf(x0); p[1] = (short)f2bf(x1);
        p[2] = (short)f2bf(x2); p[3] = (short)f2bf(x3);
        *reinterpret_cast<s16x4*>(lds + base + wB + nt * 64 + q * 16) = p;
        const unsigned pa = cp[nt * 8 + q * 2], pb = cp[nt * 8 + q * 2 + 1];
        accA[nt][4 * q + 0] = x0 + bflo(pa); accA[nt][4 * q + 1] = x1 + bfhi(pa);
        accA[nt][4 * q + 2] = x2 + bflo(pb); accA[nt][4 * q + 3] = x3 + bfhi(pb);
        accB[nt][4 * q + 0] = 0.0f; accB[nt][4 * q + 1] = 0.0f;
        accB[nt][4 * q + 2] = 0.0f; accB[nt][4 * q + 3] = 0.0f;
      }
  };

  // prologue: T writes x1 -> TA (T runs a half-step ahead of U)
  if (!grp) WB(XA);
  __syncthreads();

  // ---- 9 iterations, 2 anti-phase half-steps each ----
  #pragma unroll 1
  for (int i = 0; i < 9; ++i) {
    const int pa = XA + ((i & 1) ? 16640 : 0);
    // phase A: T computes x_{i+2}-pre from x_{i+1}; U writes x_{i+1}
    if (!grp) MSTEP(pa); else WB(pa);
    __syncthreads();
    // phase B: U computes from x_{i+1}; T writes x_{i+2}
    if (!grp) WB(pa ^ 16640); else MSTEP(pa);
    __syncthreads();
  }
  // x10_T in TB; U's acc holds x10_U pre-sthr.

  // ---- epilogue: out^T = W^T @ x^T per tile ----
  // E1: T loads Opk, GEMMs x10_T (TB), stages f32 -> TA. U writes x10_U -> UB.
  if (!grp) {
    #pragma unroll
    for (int kc = 0; kc < 16; ++kc)
      gfr[kc] = *reinterpret_cast<const s16x8*>(
          wsp + 98304u + ((unsigned)(kc * 4 + w4) * 64u + l) * 8u);
    #pragma unroll
    for (int e = 0; e < 16; ++e) { accA[0][e] = 0.0f; accB[0][e] = 0.0f; }
    __builtin_amdgcn_s_setprio(1);
    #pragma unroll
    for (int kc = 0; kc < 8; ++kc) {
      const s16x8 bA = *reinterpret_cast<const s16x8*>(lds + XB + rB + kc * 32);
      const s16x8 bB = *reinterpret_cast<const s16x8*>(lds + XB + rB + (kc + 8) * 32);
      accA[0] = __builtin_amdgcn_mfma_f32_32x32x16_bf16(gfr[kc], bA, accA[0], 0, 0, 0);
      accB[0] = __builtin_amdgcn_mfma_f32_32x32x16_bf16(gfr[kc + 8], bB, accB[0], 0, 0, 0);
    }
    __builtin_amdgcn_s_setprio(0);
    const int ob = XA + r31 * 520 + w4 * 128 + h * 16;
    #pragma unroll
    for (int q = 0; q < 4; ++q) {
      f32x4 p;
      p[0] = accA[0][4 * q + 0] + accB[0][4 * q + 0];
      p[1] = accA[0][4 * q + 1] + accB[0][4 * q + 1];
      p[2] = accA[0][4 * q + 2] + accB[0][4 * q + 2];
      p[3] = accA[0][4 * q + 3] + accB[0][4 * q + 3];
      *reinterpret_cast<f32x4*>(lds + ob + q * 32) = p;
    }
  } else {
    WB(XB);   // x10_U -> UB
  }
  __syncthreads();

  // E2: U GEMMs x10_U (UB), stages -> UA. T copies rows 0..31 to global.
  if (grp) {
    #pragma unroll
    for (int kc = 0; kc < 16; ++kc)
      gfr[kc] = *reinterpret_cast<const s16x8*>(
          wsp + 98304u + ((unsigned)(kc * 4 + w4) * 64u + l) * 8u);
    #pragma unroll
    for (int e = 0; e < 16; ++e) { accA[0][e] = 0.0f; accB[0][e] = 0.0f; }
    __builtin_amdgcn_s_setprio(1);
    #pragma unroll
    for (int kc = 0; kc < 8; ++kc) {
      const s16x8 bA = *reinterpret_cast<const s16x8*>(lds + XB + rB + kc * 32);
      const s16x8 bB = *reinterpret_cast<const s16x8*>(lds + XB + rB + (kc + 8) * 32);
      accA[0] = __builtin_amdgcn_mfma_f32_32x32x16_bf16(gfr[kc], bA, accA[0], 0, 0, 0);
      accB[0] = __builtin_amdgcn_mfma_f32_32x32x16_bf16(gfr[kc + 8], bB, accB[0], 0, 0, 0);
    }
    __builtin_amdgcn_s_setprio(0);
    const int ob = XA + r31 * 520 + w4 * 128 + h * 16;
    #pragma unroll
    for (int q = 0; q < 4; ++q) {
      f32x4 p;
      p[0] = accA[0][4 * q + 0] + accB[0][4 * q + 0];
      p[1] = accA[0][4 * q + 1] + accB[0][4 * q + 1];
      p[2] = accA[0][4 * q + 2] + accB[0][4 * q + 2];
      p[3] = accA[0][4 * q + 3] + accB[0][4 * q + 3];
      *reinterpret_cast<f32x4*>(lds + ob + q * 32) = p;
    }
  } else {
    // copy T rows (0..31) from TA; grp0 = tids 0..255
    #pragma unroll
    for (int rep = 0; rep < 4; ++rep) {
      const int flat = rep * 256 + tid;
      const int rr = flat >> 5;
      const int c4 = flat & 31;
      const f32x4 v = *reinterpret_cast<const f32x4*>(lds + rr * 520 + c4 * 16);
      *reinterpret_cast<f32x4*>(outp + (row0 + rr) * 128 + c4 * 4) = v;
    }
  }
  __syncthreads();

  // E3: all 512 threads copy U rows (32..63) from UA
  #pragma unroll
  for (int rep = 0; rep < 2; ++rep) {
    const int flat = rep * 512 + tid;
    const int rr = flat >> 5;                    // 0..31
    const int c4 = flat & 31;
    const f32x4 v = *reinterpret_cast<const f32x4*>(lds + 33280 + rr * 520 + c4 * 16);
    *reinterpret_cast<f32x4*>(outp + (row0 + 32 + rr) * 128 + c4 * 4) = v;
  }
}

extern "C" void kernel_launch(void* const* d_in, const int* in_sizes, int n_in,
                              void* d_out, int out_size, void* d_ws, size_t ws_size,
                              hipStream_t stream) {
  const float* inp = (const float*)d_in[0];
  const float* W   = (const float*)d_in[1];
  unsigned short* ws = (unsigned short*)d_ws;   // needs 256 KiB
  float* outp = (float*)d_out;
  const int B = in_sizes[0] / 128;              // 131072
  sc_prep<<<256, 64, 0, stream>>>(W, ws);
  sc_fused<<<B / 64, 512, 0, stream>>>(inp, ws, outp);
}

// Round 9
// 180.619 us; speedup vs baseline: 1.2961x; 1.2138x over previous
//
#include <hip/hip_runtime.h>
#include <hip/hip_bf16.h>

typedef __attribute__((ext_vector_type(4))) float  f32x4;
typedef __attribute__((ext_vector_type(16))) float f32x16;
typedef __attribute__((ext_vector_type(8))) short  s16x8;
typedef __attribute__((ext_vector_type(4))) short  s16x4;

#define THR_  1.0e-4f   // LR * GAMMA
#define SC_   2.0e-3f   // 2 * LR

__device__ __forceinline__ unsigned short f2bf(float f) {
  union { __hip_bfloat16 b; unsigned short u; } cv;
  cv.b = __float2bfloat16(f);
  return cv.u;
}
__device__ __forceinline__ float sthr(float v) {
  return v - fmaxf(fminf(v, THR_), -THR_);   // med3 + sub
}
__device__ __forceinline__ float bflo(unsigned u) {
  return __builtin_bit_cast(float, u << 16);
}
__device__ __forceinline__ float bfhi(unsigned u) {
  return __builtin_bit_cast(float, u & 0xffff0000u);
}

// A-frag packing for 32x32x16 (A[row][k]): lane l holds row=(l&31), k=8*(l>>5)+j.
// ws layout (unsigned short elems):
// [0,65536)     Gpk: A-frags of (-2LR*G), G=W@W^T (symmetric). frag(kc 0..15, ntg 0..7)
// [65536,98304) Cpk: A-frags of (2LR*W). frag(kc 0..7, ntg 0..7)
// [98304,131072) Opk: A-frags of W^T. frag(kc 0..15, it 0..3)
__global__ void sc_prep(const float* __restrict__ W, unsigned short* __restrict__ ws) {
  const int b = blockIdx.x;
  const int l = threadIdx.x;
  const int r = l & 31, h = l >> 5;
  if (b < 128) {                        // Gpk
    const int kc = b >> 3, ntg = b & 7;
    const int n = ntg * 32 + r;
    const int k0 = kc * 16 + 8 * h;
    float s[8];
    #pragma unroll
    for (int j = 0; j < 8; ++j) s[j] = 0.0f;
    for (int i = 0; i < 128; ++i) {
      const float wn = W[n * 128 + i];
      #pragma unroll
      for (int j = 0; j < 8; ++j) s[j] += W[(k0 + j) * 128 + i] * wn;
    }
    unsigned short* dst = ws + ((unsigned)b * 64u + l) * 8u;
    #pragma unroll
    for (int j = 0; j < 8; ++j) dst[j] = f2bf(-SC_ * s[j]);
  } else if (b < 192) {                 // Cpk
    const int bb = b - 128;
    const int kc = bb >> 3, ntg = bb & 7;
    const int n = ntg * 32 + r;
    const int k0 = kc * 16 + 8 * h;
    unsigned short* dst = ws + 65536u + ((unsigned)bb * 64u + l) * 8u;
    #pragma unroll
    for (int j = 0; j < 8; ++j) dst[j] = f2bf(SC_ * W[n * 128 + k0 + j]);
  } else {                              // Opk
    const int bb = b - 192;
    const int kc = bb >> 2, it = bb & 3;
    const int i = it * 32 + r;
    const int n0 = kc * 16 + 8 * h;
    unsigned short* dst = ws + 98304u + ((unsigned)bb * 64u + l) * 8u;
    #pragma unroll
    for (int j = 0; j < 8; ++j) dst[j] = f2bf(W[(n0 + j) * 128 + i]);
  }
}

// Swapped-operand 32x32x16 structure (R6 = 179.7us baseline). R9 change:
// FIXED anti-phase stagger. Co-resident block pairs are (b, b+2048) under the
// 8-XCD round-robin dispatcher (or (b, b+1) if consecutive); R6's (b>>8)&1 has
// equal parity for both members in BOTH patterns -> stagger never engaged.
// ((b>>11) ^ b) & 1 flips for both patterns. Sleep ~1216 cyc (~half a step),
// placed after the c-phase so global-load staging still overlaps across blocks.
// Once offset, anti-phase is self-sustaining: A.mfma(LDS+MFMA pipes) overlaps
// B.writeback(VALU pipe) with no shared-pipe contention.
// NOTE: working set ~230 unified regs -> ONLY __launch_bounds__(256,2) is legal
// ((256,4) caps allocator at 64-128 and spills GBs to scratch: R2/R4/R7).
__global__ __launch_bounds__(256, 2) void sc_fused(
    const float* __restrict__ inp,
    const unsigned short* __restrict__ wsp,
    float* __restrict__ outp)
{
  __shared__ __align__(16) unsigned char lds[33280];  // XB0 [0,16640), XB1/INB [16640,33280)

  const int tid = threadIdx.x;
  const int l = tid & 63;
  const int w = tid >> 6;          // 0..3
  const int h = l >> 5;            // 0..1
  const int r31 = l & 31;
  const long row0 = (long)blockIdx.x * 32;

  // B-read base (x): row=l&31, k-col byte = kc*32 + h*16
  const int rB0 = r31 * 520 + h * 16;
  const int rB1 = rB0 + 16640;
  // x-write base: row=l&31, n = w*64 + nt*32 + q*8 + 4h (+s)
  const int wB0 = r31 * 520 + h * 8 + w * 128;
  const int wB1 = wB0 + 16640;

  // ---- stage inputs -> XB1 area, row-major bf16, stride 264 B ----
  #pragma unroll
  for (int rep = 0; rep < 4; ++rep) {
    const int flat = rep * 256 + tid;            // 0..1023 float4s
    const int rr = flat >> 5;                    // row 0..31
    const int c4 = flat & 31;
    const f32x4 v = *reinterpret_cast<const f32x4*>(inp + (row0 + rr) * 128 + c4 * 4);
    s16x4 p;
    p[0] = (short)f2bf(v[0]); p[1] = (short)f2bf(v[1]);
    p[2] = (short)f2bf(v[2]); p[3] = (short)f2bf(v[3]);
    *reinterpret_cast<s16x4*>(lds + 16640 + rr * 264 + c4 * 8) = p;
  }

  // ---- c-phase A-frags (2LR*W) ----
  s16x8 gfr[32];
  #pragma unroll
  for (int kc = 0; kc < 8; ++kc)
    #pragma unroll
    for (int nt = 0; nt < 2; ++nt)
      gfr[kc * 2 + nt] = *reinterpret_cast<const s16x8*>(
          wsp + 65536u + ((unsigned)(kc * 8 + w * 2 + nt) * 64u + l) * 8u);

  __syncthreads();

  // ---- c = 2LR * W @ in^T (K-split: kc0-3 -> accA, kc4-7 -> accB) ----
  f32x16 accA[2], accB[2], creg[2];
  #pragma unroll
  for (int nt = 0; nt < 2; ++nt)
    #pragma unroll
    for (int e = 0; e < 16; ++e) { accA[nt][e] = 0.0f; accB[nt][e] = 0.0f; }

  const int ib = 16640 + r31 * 264 + h * 16;
  #pragma unroll
  for (int kc = 0; kc < 4; ++kc) {
    const s16x8 bA = *reinterpret_cast<const s16x8*>(lds + ib + kc * 32);
    const s16x8 bB = *reinterpret_cast<const s16x8*>(lds + ib + (kc + 4) * 32);
    __builtin_amdgcn_s_setprio(1);
    #pragma unroll
    for (int nt = 0; nt < 2; ++nt)
      accA[nt] = __builtin_amdgcn_mfma_f32_32x32x16_bf16(gfr[kc * 2 + nt], bA, accA[nt], 0, 0, 0);
    #pragma unroll
    for (int nt = 0; nt < 2; ++nt)
      accB[nt] = __builtin_amdgcn_mfma_f32_32x32x16_bf16(gfr[(kc + 4) * 2 + nt], bB, accB[nt], 0, 0, 0);
    __builtin_amdgcn_s_setprio(0);
  }

  // x1 = sthr(c); write x1 -> XB0; pre-init accA = x1 + creg, accB = 0
  #pragma unroll
  for (int nt = 0; nt < 2; ++nt)
    #pragma unroll
    for (int q = 0; q < 4; ++q) {
      float f0 = accA[nt][4 * q + 0] + accB[nt][4 * q + 0];
      float f1 = accA[nt][4 * q + 1] + accB[nt][4 * q + 1];
      float f2 = accA[nt][4 * q + 2] + accB[nt][4 * q + 2];
      float f3 = accA[nt][4 * q + 3] + accB[nt][4 * q + 3];
      creg[nt][4 * q + 0] = f0; creg[nt][4 * q + 1] = f1;
      creg[nt][4 * q + 2] = f2; creg[nt][4 * q + 3] = f3;
      f0 = sthr(f0); f1 = sthr(f1); f2 = sthr(f2); f3 = sthr(f3);
      s16x4 p;
      p[0] = (short)f2bf(f0); p[1] = (short)f2bf(f1);
      p[2] = (short)f2bf(f2); p[3] = (short)f2bf(f3);
      *reinterpret_cast<s16x4*>(lds + wB0 + nt * 64 + q * 16) = p;
      accA[nt][4 * q + 0] = f0 + creg[nt][4 * q + 0];
      accA[nt][4 * q + 1] = f1 + creg[nt][4 * q + 1];
      accA[nt][4 * q + 2] = f2 + creg[nt][4 * q + 2];
      accA[nt][4 * q + 3] = f3 + creg[nt][4 * q + 3];
      accB[nt][4 * q + 0] = 0.0f; accB[nt][4 * q + 1] = 0.0f;
      accB[nt][4 * q + 2] = 0.0f; accB[nt][4 * q + 3] = 0.0f;
    }

  // ---- step A-frags (-2LR*G) ----
  #pragma unroll
  for (int kc = 0; kc < 16; ++kc)
    #pragma unroll
    for (int nt = 0; nt < 2; ++nt)
      gfr[kc * 2 + nt] = *reinterpret_cast<const s16x8*>(
          wsp + ((unsigned)(kc * 8 + w * 2 + nt) * 64u + l) * 8u);

  // ---- anti-phase stagger: offset the step loop by ~half a step (~1216 cyc).
  // Covers co-resident pairings (b,b+1) AND (b,b+2048): XOR flips for both.
  if (((blockIdx.x >> 11) ^ blockIdx.x) & 1) {
    __builtin_amdgcn_s_sleep(15);
    __builtin_amdgcn_s_sleep(4);
  }

  // ---- one ISTA step. Entry invariant: accA = x + creg, accB = 0, x in rb.
  auto STEP = [&](const int rb, const int wb) {
    __syncthreads();
    #pragma unroll
    for (int kc = 0; kc < 8; ++kc) {
      const s16x8 bA = *reinterpret_cast<const s16x8*>(lds + rb + kc * 32);
      const s16x8 bB = *reinterpret_cast<const s16x8*>(lds + rb + (kc + 8) * 32);
      __builtin_amdgcn_s_setprio(1);
      #pragma unroll
      for (int nt = 0; nt < 2; ++nt)
        accA[nt] = __builtin_amdgcn_mfma_f32_32x32x16_bf16(gfr[kc * 2 + nt], bA, accA[nt], 0, 0, 0);
      #pragma unroll
      for (int nt = 0; nt < 2; ++nt)
        accB[nt] = __builtin_amdgcn_mfma_f32_32x32x16_bf16(gfr[(kc + 8) * 2 + nt], bB, accB[nt], 0, 0, 0);
      __builtin_amdgcn_s_setprio(0);
    }
    #pragma unroll
    for (int nt = 0; nt < 2; ++nt)
      #pragma unroll
      for (int q = 0; q < 4; ++q) {
        float f0 = sthr(accA[nt][4 * q + 0] + accB[nt][4 * q + 0]);
        float f1 = sthr(accA[nt][4 * q + 1] + accB[nt][4 * q + 1]);
        float f2 = sthr(accA[nt][4 * q + 2] + accB[nt][4 * q + 2]);
        float f3 = sthr(accA[nt][4 * q + 3] + accB[nt][4 * q + 3]);
        s16x4 p;
        p[0] = (short)f2bf(f0); p[1] = (short)f2bf(f1);
        p[2] = (short)f2bf(f2); p[3] = (short)f2bf(f3);
        *reinterpret_cast<s16x4*>(lds + wb + nt * 64 + q * 16) = p;
        accA[nt][4 * q + 0] = f0 + creg[nt][4 * q + 0];
        accA[nt][4 * q + 1] = f1 + creg[nt][4 * q + 1];
        accA[nt][4 * q + 2] = f2 + creg[nt][4 * q + 2];
        accA[nt][4 * q + 3] = f3 + creg[nt][4 * q + 3];
        accB[nt][4 * q + 0] = 0.0f; accB[nt][4 * q + 1] = 0.0f;
        accB[nt][4 * q + 2] = 0.0f; accB[nt][4 * q + 3] = 0.0f;
      }
  };

  // 9 steps: x1 in XB0; alternate; x10 lands in XB1
  #pragma unroll 1
  for (int p = 0; p < 4; ++p) {
    STEP(rB0, wB1);
    STEP(rB1, wB0);
  }
  STEP(rB0, wB1);

  // ---- out^T = W^T @ x^T ; wave w owns out cols [w*32, w*32+32) ----
  __syncthreads();
  #pragma unroll
  for (int kc = 0; kc < 16; ++kc)
    gfr[kc] = *reinterpret_cast<const s16x8*>(
        wsp + 98304u + ((unsigned)(kc * 4 + w) * 64u + l) * 8u);
  f32x16 oA, oB;
  #pragma unroll
  for (int e = 0; e < 16; ++e) { oA[e] = 0.0f; oB[e] = 0.0f; }
  #pragma unroll
  for (int kc = 0; kc < 8; ++kc) {
    const s16x8 bA = *reinterpret_cast<const s16x8*>(lds + rB1 + kc * 32);
    const s16x8 bB = *reinterpret_cast<const s16x8*>(lds + rB1 + (kc + 8) * 32);
    __builtin_amdgcn_s_setprio(1);
    oA = __builtin_amdgcn_mfma_f32_32x32x16_bf16(gfr[kc], bA, oA, 0, 0, 0);
    oB = __builtin_amdgcn_mfma_f32_32x32x16_bf16(gfr[kc + 8], bB, oB, 0, 0, 0);
    __builtin_amdgcn_s_setprio(0);
  }
  // stage out f32 to XB0: out[m][i], m=l&31, i = w*32 + q*8 + 4h (+s); stride 520
  const int ob = r31 * 520 + h * 16 + w * 128;
  #pragma unroll
  for (int q = 0; q < 4; ++q) {
    f32x4 p;
    p[0] = oA[4 * q + 0] + oB[4 * q + 0]; p[1] = oA[4 * q + 1] + oB[4 * q + 1];
    p[2] = oA[4 * q + 2] + oB[4 * q + 2]; p[3] = oA[4 * q + 3] + oB[4 * q + 3];
    *reinterpret_cast<f32x4*>(lds + ob + q * 32) = p;
  }
  __syncthreads();
  // coalesced copy 32 rows x 128 f32 -> global
  #pragma unroll
  for (int rep = 0; rep < 4; ++rep) {
    const int flat = rep * 256 + tid;
    const int rr = flat >> 5;
    const int c4 = flat & 31;
    const f32x4 v = *reinterpret_cast<const f32x4*>(lds + rr * 520 + c4 * 16);
    *reinterpret_cast<f32x4*>(outp + (row0 + rr) * 128 + c4 * 4) = v;
  }
}

extern "C" void kernel_launch(void* const* d_in, const int* in_sizes, int n_in,
                              void* d_out, int out_size, void* d_ws, size_t ws_size,
                              hipStream_t stream) {
  const float* inp = (const float*)d_in[0];
  const float* W   = (const float*)d_in[1];
  unsigned short* ws = (unsigned short*)d_ws;   // needs 256 KiB
  float* outp = (float*)d_out;
  const int B = in_sizes[0] / 128;              // 131072
  sc_prep<<<256, 64, 0, stream>>>(W, ws);
  sc_fused<<<B / 32, 256, 0, stream>>>(inp, ws, outp);
}

// Round 10
// 176.568 us; speedup vs baseline: 1.3258x; 1.0229x over previous
//
#include <hip/hip_runtime.h>
#include <hip/hip_bf16.h>

typedef __attribute__((ext_vector_type(4))) float  f32x4;
typedef __attribute__((ext_vector_type(16))) float f32x16;
typedef __attribute__((ext_vector_type(8))) short  s16x8;
typedef __attribute__((ext_vector_type(4))) short  s16x4;

#define THR_  1.0e-4f   // LR * GAMMA
#define SC_   2.0e-3f   // 2 * LR

__device__ __forceinline__ unsigned short f2bf(float f) {
  union { __hip_bfloat16 b; unsigned short u; } cv;
  cv.b = __float2bfloat16(f);
  return cv.u;
}
__device__ __forceinline__ float sthr(float v) {
  return v - fmaxf(fminf(v, THR_), -THR_);   // med3 + sub
}
__device__ __forceinline__ float bflo(unsigned u) {
  return __builtin_bit_cast(float, u << 16);
}
__device__ __forceinline__ float bfhi(unsigned u) {
  return __builtin_bit_cast(float, u & 0xffff0000u);
}

// A-frag packing for 32x32x16 (A[row][k]): lane l holds row=(l&31), k=8*(l>>5)+j.
// ws layout (unsigned short elems):
// [0,65536)     Gpk: A-frags of (-2LR*G), G=W@W^T (symmetric). frag(kc 0..15, ntg 0..7)
// [65536,98304) Cpk: A-frags of (2LR*W). frag(kc 0..7, ntg 0..7)
// [98304,131072) Opk: A-frags of W^T. frag(kc 0..15, it 0..3)
__global__ void sc_prep(const float* __restrict__ W, unsigned short* __restrict__ ws) {
  const int b = blockIdx.x;
  const int l = threadIdx.x;
  const int r = l & 31, h = l >> 5;
  if (b < 128) {                        // Gpk
    const int kc = b >> 3, ntg = b & 7;
    const int n = ntg * 32 + r;
    const int k0 = kc * 16 + 8 * h;
    float s[8];
    #pragma unroll
    for (int j = 0; j < 8; ++j) s[j] = 0.0f;
    for (int i = 0; i < 128; ++i) {
      const float wn = W[n * 128 + i];
      #pragma unroll
      for (int j = 0; j < 8; ++j) s[j] += W[(k0 + j) * 128 + i] * wn;
    }
    unsigned short* dst = ws + ((unsigned)b * 64u + l) * 8u;
    #pragma unroll
    for (int j = 0; j < 8; ++j) dst[j] = f2bf(-SC_ * s[j]);
  } else if (b < 192) {                 // Cpk
    const int bb = b - 128;
    const int kc = bb >> 3, ntg = bb & 7;
    const int n = ntg * 32 + r;
    const int k0 = kc * 16 + 8 * h;
    unsigned short* dst = ws + 65536u + ((unsigned)bb * 64u + l) * 8u;
    #pragma unroll
    for (int j = 0; j < 8; ++j) dst[j] = f2bf(SC_ * W[n * 128 + k0 + j]);
  } else {                              // Opk
    const int bb = b - 192;
    const int kc = bb >> 2, it = bb & 3;
    const int i = it * 32 + r;
    const int n0 = kc * 16 + 8 * h;
    unsigned short* dst = ws + 98304u + ((unsigned)bb * 64u + l) * 8u;
    #pragma unroll
    for (int j = 0; j < 8; ++j) dst[j] = f2bf(W[(n0 + j) * 128 + i]);
  }
}

// Swapped-operand 32x32x16 structure (R6 baseline = 179.7us). R10 changes:
//  (1) creg f32 -> packed bf16x2 cp[16]: -16 VGPR pressure (numerics proven R7/R8)
//  (2) depth-2 software rotation of x B-frags in STEP: loads for kc+2 issue
//      while kc's MFMAs execute -> ds_read latency (~120cy) hidden even at
//      high register pressure (theory: compiler couldn't hoist >2-4 reads
//      at ~230 live regs -> ~55% of each step was exposed LDS latency)
//  (3) setprio once around the MFMA phase (not 16 toggles/step)
// NOTE: working set ~215 unified regs -> ONLY __launch_bounds__(256,2) is
// legal ((256,4) caps allocator and spills GBs to scratch: R2/R4/R7).
__global__ __launch_bounds__(256, 2) void sc_fused(
    const float* __restrict__ inp,
    const unsigned short* __restrict__ wsp,
    float* __restrict__ outp)
{
  __shared__ __align__(16) unsigned char lds[33280];  // XB0 [0,16640), XB1/INB [16640,33280)

  const int tid = threadIdx.x;
  const int l = tid & 63;
  const int w = tid >> 6;          // 0..3
  const int h = l >> 5;            // 0..1
  const int r31 = l & 31;
  const long row0 = (long)blockIdx.x * 32;

  // B-read base (x): row=l&31, k-col byte = kc*32 + h*16
  const int rB0 = r31 * 520 + h * 16;
  const int rB1 = rB0 + 16640;
  // x-write base: row=l&31, n = w*64 + nt*32 + q*8 + 4h (+s)
  const int wB0 = r31 * 520 + h * 8 + w * 128;
  const int wB1 = wB0 + 16640;

  // ---- stage inputs -> XB1 area, row-major bf16, stride 264 B ----
  #pragma unroll
  for (int rep = 0; rep < 4; ++rep) {
    const int flat = rep * 256 + tid;            // 0..1023 float4s
    const int rr = flat >> 5;                    // row 0..31
    const int c4 = flat & 31;
    const f32x4 v = *reinterpret_cast<const f32x4*>(inp + (row0 + rr) * 128 + c4 * 4);
    s16x4 p;
    p[0] = (short)f2bf(v[0]); p[1] = (short)f2bf(v[1]);
    p[2] = (short)f2bf(v[2]); p[3] = (short)f2bf(v[3]);
    *reinterpret_cast<s16x4*>(lds + 16640 + rr * 264 + c4 * 8) = p;
  }

  // ---- c-phase A-frags (2LR*W) ----
  s16x8 gfr[32];
  #pragma unroll
  for (int kc = 0; kc < 8; ++kc)
    #pragma unroll
    for (int nt = 0; nt < 2; ++nt)
      gfr[kc * 2 + nt] = *reinterpret_cast<const s16x8*>(
          wsp + 65536u + ((unsigned)(kc * 8 + w * 2 + nt) * 64u + l) * 8u);

  __syncthreads();

  // ---- c = 2LR * W @ in^T (K-split: kc0-3 -> accA, kc4-7 -> accB) ----
  f32x16 accA[2], accB[2];
  #pragma unroll
  for (int nt = 0; nt < 2; ++nt)
    #pragma unroll
    for (int e = 0; e < 16; ++e) { accA[nt][e] = 0.0f; accB[nt][e] = 0.0f; }

  const int ib = 16640 + r31 * 264 + h * 16;
  #pragma unroll
  for (int kc = 0; kc < 4; ++kc) {
    const s16x8 bA = *reinterpret_cast<const s16x8*>(lds + ib + kc * 32);
    const s16x8 bB = *reinterpret_cast<const s16x8*>(lds + ib + (kc + 4) * 32);
    __builtin_amdgcn_s_setprio(1);
    #pragma unroll
    for (int nt = 0; nt < 2; ++nt)
      accA[nt] = __builtin_amdgcn_mfma_f32_32x32x16_bf16(gfr[kc * 2 + nt], bA, accA[nt], 0, 0, 0);
    #pragma unroll
    for (int nt = 0; nt < 2; ++nt)
      accB[nt] = __builtin_amdgcn_mfma_f32_32x32x16_bf16(gfr[(kc + 4) * 2 + nt], bB, accB[nt], 0, 0, 0);
    __builtin_amdgcn_s_setprio(0);
  }

  // c packed to bf16x2 (16 regs); x1 = sthr(c) -> XB0; preinit accA = x1+c_bf
  unsigned cp[16];
  #pragma unroll
  for (int nt = 0; nt < 2; ++nt)
    #pragma unroll
    for (int j = 0; j < 8; ++j) {
      const float e0 = accA[nt][2 * j + 0] + accB[nt][2 * j + 0];
      const float e1 = accA[nt][2 * j + 1] + accB[nt][2 * j + 1];
      cp[nt * 8 + j] = (unsigned)f2bf(e0) | ((unsigned)f2bf(e1) << 16);
    }
  #pragma unroll
  for (int nt = 0; nt < 2; ++nt)
    #pragma unroll
    for (int q = 0; q < 4; ++q) {
      const unsigned pa = cp[nt * 8 + q * 2], pb = cp[nt * 8 + q * 2 + 1];
      float f0 = sthr(accA[nt][4 * q + 0] + accB[nt][4 * q + 0]);
      float f1 = sthr(accA[nt][4 * q + 1] + accB[nt][4 * q + 1]);
      float f2 = sthr(accA[nt][4 * q + 2] + accB[nt][4 * q + 2]);
      float f3 = sthr(accA[nt][4 * q + 3] + accB[nt][4 * q + 3]);
      s16x4 p;
      p[0] = (short)f2bf(f0); p[1] = (short)f2bf(f1);
      p[2] = (short)f2bf(f2); p[3] = (short)f2bf(f3);
      *reinterpret_cast<s16x4*>(lds + wB0 + nt * 64 + q * 16) = p;
      accA[nt][4 * q + 0] = f0 + bflo(pa); accA[nt][4 * q + 1] = f1 + bfhi(pa);
      accA[nt][4 * q + 2] = f2 + bflo(pb); accA[nt][4 * q + 3] = f3 + bfhi(pb);
      accB[nt][4 * q + 0] = 0.0f; accB[nt][4 * q + 1] = 0.0f;
      accB[nt][4 * q + 2] = 0.0f; accB[nt][4 * q + 3] = 0.0f;
    }

  // ---- step A-frags (-2LR*G) ----
  #pragma unroll
  for (int kc = 0; kc < 16; ++kc)
    #pragma unroll
    for (int nt = 0; nt < 2; ++nt)
      gfr[kc * 2 + nt] = *reinterpret_cast<const s16x8*>(
          wsp + ((unsigned)(kc * 8 + w * 2 + nt) * 64u + l) * 8u);

  // ---- one ISTA step. Entry invariant: accA = x + c_bf, accB = 0, x in rb.
  // B-frags software-rotated depth 2: kc+2's loads issue during kc's MFMAs.
  auto STEP = [&](const int rb, const int wb) {
    __syncthreads();
    s16x8 a0 = *reinterpret_cast<const s16x8*>(lds + rb + 0 * 32);
    s16x8 b0 = *reinterpret_cast<const s16x8*>(lds + rb + 8 * 32);
    s16x8 a1 = *reinterpret_cast<const s16x8*>(lds + rb + 1 * 32);
    s16x8 b1 = *reinterpret_cast<const s16x8*>(lds + rb + 9 * 32);
    __builtin_amdgcn_s_setprio(1);
    #pragma unroll
    for (int kc = 0; kc < 8; ++kc) {
      s16x8 a2 = a1, b2 = b1;
      if (kc < 6) {
        a2 = *reinterpret_cast<const s16x8*>(lds + rb + (kc + 2) * 32);
        b2 = *reinterpret_cast<const s16x8*>(lds + rb + (kc + 10) * 32);
      }
      accA[0] = __builtin_amdgcn_mfma_f32_32x32x16_bf16(gfr[kc * 2 + 0], a0, accA[0], 0, 0, 0);
      accA[1] = __builtin_amdgcn_mfma_f32_32x32x16_bf16(gfr[kc * 2 + 1], a0, accA[1], 0, 0, 0);
      accB[0] = __builtin_amdgcn_mfma_f32_32x32x16_bf16(gfr[(kc + 8) * 2 + 0], b0, accB[0], 0, 0, 0);
      accB[1] = __builtin_amdgcn_mfma_f32_32x32x16_bf16(gfr[(kc + 8) * 2 + 1], b0, accB[1], 0, 0, 0);
      a0 = a1; b0 = b1; a1 = a2; b1 = b2;
    }
    __builtin_amdgcn_s_setprio(0);
    #pragma unroll
    for (int nt = 0; nt < 2; ++nt)
      #pragma unroll
      for (int q = 0; q < 4; ++q) {
        const unsigned pa = cp[nt * 8 + q * 2], pb = cp[nt * 8 + q * 2 + 1];
        float f0 = sthr(accA[nt][4 * q + 0] + accB[nt][4 * q + 0]);
        float f1 = sthr(accA[nt][4 * q + 1] + accB[nt][4 * q + 1]);
        float f2 = sthr(accA[nt][4 * q + 2] + accB[nt][4 * q + 2]);
        float f3 = sthr(accA[nt][4 * q + 3] + accB[nt][4 * q + 3]);
        s16x4 p;
        p[0] = (short)f2bf(f0); p[1] = (short)f2bf(f1);
        p[2] = (short)f2bf(f2); p[3] = (short)f2bf(f3);
        *reinterpret_cast<s16x4*>(lds + wb + nt * 64 + q * 16) = p;
        accA[nt][4 * q + 0] = f0 + bflo(pa); accA[nt][4 * q + 1] = f1 + bfhi(pa);
        accA[nt][4 * q + 2] = f2 + bflo(pb); accA[nt][4 * q + 3] = f3 + bfhi(pb);
        accB[nt][4 * q + 0] = 0.0f; accB[nt][4 * q + 1] = 0.0f;
        accB[nt][4 * q + 2] = 0.0f; accB[nt][4 * q + 3] = 0.0f;
      }
  };

  // 9 steps: x1 in XB0; alternate; x10 lands in XB1
  #pragma unroll 1
  for (int p = 0; p < 4; ++p) {
    STEP(rB0, wB1);
    STEP(rB1, wB0);
  }
  STEP(rB0, wB1);

  // ---- out^T = W^T @ x^T ; wave w owns out cols [w*32, w*32+32) ----
  __syncthreads();
  #pragma unroll
  for (int kc = 0; kc < 16; ++kc)
    gfr[kc] = *reinterpret_cast<const s16x8*>(
        wsp + 98304u + ((unsigned)(kc * 4 + w) * 64u + l) * 8u);
  f32x16 oA, oB;
  #pragma unroll
  for (int e = 0; e < 16; ++e) { oA[e] = 0.0f; oB[e] = 0.0f; }
  #pragma unroll
  for (int kc = 0; kc < 8; ++kc) {
    const s16x8 bA = *reinterpret_cast<const s16x8*>(lds + rB1 + kc * 32);
    const s16x8 bB = *reinterpret_cast<const s16x8*>(lds + rB1 + (kc + 8) * 32);
    __builtin_amdgcn_s_setprio(1);
    oA = __builtin_amdgcn_mfma_f32_32x32x16_bf16(gfr[kc], bA, oA, 0, 0, 0);
    oB = __builtin_amdgcn_mfma_f32_32x32x16_bf16(gfr[kc + 8], bB, oB, 0, 0, 0);
    __builtin_amdgcn_s_setprio(0);
  }
  // stage out f32 to XB0: out[m][i], m=l&31, i = w*32 + q*8 + 4h (+s); stride 520
  const int ob = r31 * 520 + h * 16 + w * 128;
  #pragma unroll
  for (int q = 0; q < 4; ++q) {
    f32x4 p;
    p[0] = oA[4 * q + 0] + oB[4 * q + 0]; p[1] = oA[4 * q + 1] + oB[4 * q + 1];
    p[2] = oA[4 * q + 2] + oB[4 * q + 2]; p[3] = oA[4 * q + 3] + oB[4 * q + 3];
    *reinterpret_cast<f32x4*>(lds + ob + q * 32) = p;
  }
  __syncthreads();
  // coalesced copy 32 rows x 128 f32 -> global
  #pragma unroll
  for (int rep = 0; rep < 4; ++rep) {
    const int flat = rep * 256 + tid;
    const int rr = flat >> 5;
    const int c4 = flat & 31;
    const f32x4 v = *reinterpret_cast<const f32x4*>(lds + rr * 520 + c4 * 16);
    *reinterpret_cast<f32x4*>(outp + (row0 + rr) * 128 + c4 * 4) = v;
  }
}

extern "C" void kernel_launch(void* const* d_in, const int* in_sizes, int n_in,
                              void* d_out, int out_size, void* d_ws, size_t ws_size,
                              hipStream_t stream) {
  const float* inp = (const float*)d_in[0];
  const float* W   = (const float*)d_in[1];
  unsigned short* ws = (unsigned short*)d_ws;   // needs 256 KiB
  float* outp = (float*)d_out;
  const int B = in_sizes[0] / 128;              // 131072
  sc_prep<<<256, 64, 0, stream>>>(W, ws);
  sc_fused<<<B / 32, 256, 0, stream>>>(inp, ws, outp);
}